// Round 4
// baseline (1078.551 us; speedup 1.0000x reference)
//
#include <hip/hip_runtime.h>

#define NTOK 4096
#define DM 1024
#define DH 4096
#define NE 8

typedef __attribute__((ext_vector_type(8))) short bf16x8;
typedef __attribute__((ext_vector_type(4))) float f32x4;
typedef __attribute__((ext_vector_type(8))) unsigned short u16x8;

__device__ __forceinline__ ushort f2bf(float f) {
  union { float f; unsigned u; } v; v.f = f;
  unsigned r = v.u + 0x7fffu + ((v.u >> 16) & 1u);
  return (ushort)(r >> 16);
}

#define GL2LDS(g, l) __builtin_amdgcn_global_load_lds( \
    (__attribute__((address_space(1))) const void*)(g), \
    (__attribute__((address_space(3))) void*)(l), 16, 0, 0)

// ---------------- gating: logits, top-2, softmax, counts ----------------
__global__ __launch_bounds__(256) void gate_kernel(
    const float* __restrict__ x, const float* __restrict__ Wg,
    const float* __restrict__ bg, int* __restrict__ tkE,
    float* __restrict__ tkW, int* __restrict__ gcnt)
{
  const int wave = threadIdx.x >> 6;
  const int lane = threadIdx.x & 63;
  const int t = blockIdx.x * 4 + wave;

  float acc[NE];
#pragma unroll
  for (int e = 0; e < NE; e++) acc[e] = 0.f;

  for (int i = 0; i < DM / 64; i++) {
    int d = i * 64 + lane;
    float xv = x[(long)t * DM + d];
#pragma unroll
    for (int e = 0; e < NE; e++) acc[e] += xv * Wg[d * NE + e];
  }
#pragma unroll
  for (int e = 0; e < NE; e++) {
#pragma unroll
    for (int off = 32; off; off >>= 1) acc[e] += __shfl_xor(acc[e], off, 64);
    acc[e] += bg[e];
  }
  int e0 = 0; float v0 = acc[0];
#pragma unroll
  for (int e = 1; e < NE; e++) if (acc[e] > v0) { v0 = acc[e]; e0 = e; }
  int e1 = -1; float v1 = -3.4e38f;
#pragma unroll
  for (int e = 0; e < NE; e++) if (e != e0 && acc[e] > v1) { v1 = acc[e]; e1 = e; }
  float w0 = 1.f / (1.f + __expf(v1 - v0));
  float w1 = 1.f - w0;
  if (lane == 0) {
    tkE[t] = e0 | (e1 << 8);
    tkW[2 * t] = w0;
    tkW[2 * t + 1] = w1;
    atomicAdd(&gcnt[e0], 1);
    atomicAdd(&gcnt[e1], 1);
  }
}

// ---------------- exclusive scan of counts ----------
__global__ void scan_kernel(const int* __restrict__ gcnt, int* __restrict__ offs,
                            int* __restrict__ cursor)
{
  if (threadIdx.x == 0) {
    int o = 0;
    for (int e = 0; e < NE; e++) { offs[e] = o; o += gcnt[e]; cursor[e] = 0; }
    offs[NE] = o;
  }
}

// ---------------- build packed row lists ----------------
__global__ __launch_bounds__(256) void build_kernel(
    const int* __restrict__ tkE, const float* __restrict__ tkW,
    const int* __restrict__ offs, int* __restrict__ cursor,
    int* __restrict__ rmeta, float* __restrict__ rw)
{
  int t = blockIdx.x * 256 + threadIdx.x;
  int ee = tkE[t];
#pragma unroll
  for (int k = 0; k < 2; k++) {
    int e = (k == 0) ? (ee & 0xff) : (ee >> 8);
    int pos = atomicAdd(&cursor[e], 1);
    int row = offs[e] + pos;
    rmeta[row] = t * 2 + k;
    rw[row] = tkW[t * 2 + k];
  }
}

// ---------------- gather x rows -> packed bf16 A matrix ----------------
__global__ __launch_bounds__(256) void gather_kernel(
    const float* __restrict__ x, const int* __restrict__ rmeta,
    ushort* __restrict__ xg)
{
  int row = blockIdx.x;
  int t = rmeta[row] >> 1;
  const float4* src = (const float4*)(x + (long)t * DM);
  float4 v = src[threadIdx.x];
  ushort4 o = { f2bf(v.x), f2bf(v.y), f2bf(v.z), f2bf(v.w) };
  *(ushort4*)(xg + (long)row * DM + threadIdx.x * 4) = o;
}

// ---------------- transpose + fp32->bf16 convert (64x64 tiles) ----------
__global__ __launch_bounds__(256) void transpose_cvt(
    const float* __restrict__ src, ushort* __restrict__ dst,
    int R, int C, long srcE, long dstE)
{
  __shared__ __align__(16) float tile[64][68];
  const int e = blockIdx.z;
  const int r0 = blockIdx.y * 64;
  const int c0 = blockIdx.x * 64;
  const float* s = src + (long)e * srcE;
  ushort* d = dst + (long)e * dstE;
  const int tid = threadIdx.x;
  const int lr = tid >> 4;      // 0..15
  const int lc4 = tid & 15;     // float4 col 0..15
#pragma unroll
  for (int p = 0; p < 4; p++) {
    int r = p * 16 + lr;
    float4 v = *(const float4*)&s[(long)(r0 + r) * C + c0 + lc4 * 4];
    *(float4*)&tile[r][lc4 * 4] = v;
  }
  __syncthreads();
  const int oc = tid >> 2;      // output row (= src col) 0..63
  const int seg = tid & 3;      // 16B segment
  u16x8 o0, o1;
#pragma unroll
  for (int j = 0; j < 8; j++) {
    o0[j] = f2bf(tile[seg * 8 + j][oc]);
    o1[j] = f2bf(tile[32 + seg * 8 + j][oc]);
  }
  ushort* dp = &d[(long)(c0 + oc) * R + r0];
  *(u16x8*)(dp + seg * 8) = o0;
  *(u16x8*)(dp + 32 + seg * 8) = o1;
}

// ================= GEMM1: 8-phase counted-vmcnt schedule ================
// BM=256 x BN=128(dual h,g), BK=64. 8 waves (4M x 2N), per-wave 64x64 dual.
// LDS 128KB total. Per-buffer sizes (BYTES): A 32768, Bh/Bg 16384 each.
// T2 XOR swizzle (seg ^= row&7) on BOTH the pre-swizzled gl2lds global
// source and the ds_read side (rule 21). 8 gl2lds/thread per K-tile;
// pipeline 2 tiles deep: steady-state wait vmcnt(8), tail vmcnt(0).
__global__ __launch_bounds__(512, 2) void gemm1_kernel(
    const ushort* __restrict__ xg, const ushort* __restrict__ Wt01,
    const float* __restrict__ b0, const float* __restrict__ b1,
    const int* __restrict__ offs, ushort* __restrict__ aout)
{
  const int flat = blockIdx.x;       // 0..2047
  const int xcd = flat & 7;
  const int rest = flat >> 3;
  const int mt = rest & 7;           // 8 mt tiles of 256 rows (cnt<=2048)
  const int g2 = rest >> 3;          // 0..31
  const int val = g2 * 8 + xcd;      // 0..255 ; mt-siblings share XCD
  const int e = val >> 5;
  const int nt = val & 31;

  const int off_e = offs[e];
  const int cnt = offs[e + 1] - off_e;
  if (mt * 256 >= cnt) return;
  const int nbase = nt * 128;

  __shared__ ushort As[2 * 256 * 64];   // 64 KB (32 KB per buffer)
  __shared__ ushort Bh[2 * 128 * 64];   // 32 KB (16 KB per buffer)
  __shared__ ushort Bg[2 * 128 * 64];   // 32 KB (16 KB per buffer)

  const int tid = threadIdx.x;
  const int lane = tid & 63;
  const int wave = tid >> 6;
  const int wm = wave & 3;           // 0..3
  const int wn = wave >> 2;          // 0..1

  const ushort* Ap = xg + (long)(off_e + mt * 256) * DM;
  const ushort* Bhp = Wt01 + (long)e * (2 * DH) * DM + (long)nbase * DM;
  const ushort* Bgp = Bhp + (long)DH * DM;

  f32x4 acc_h[4][4], acc_g[4][4];
#pragma unroll
  for (int i = 0; i < 4; i++)
#pragma unroll
    for (int j = 0; j < 4; j++) {
      acc_h[i][j] = (f32x4){0.f, 0.f, 0.f, 0.f};
      acc_g[i][j] = (f32x4){0.f, 0.f, 0.f, 0.f};
    }

  auto stage = [&](int cur, int k0) {
#pragma unroll
    for (int s = 0; s < 4; s++) {
      int loff = s * 8192 + tid * 16;
      int row = loff >> 7;
      int sg = ((loff >> 4) & 7) ^ (row & 7);
      GL2LDS(Ap + (long)row * DM + k0 + sg * 8, (char*)As + cur * 32768 + loff);
    }
#pragma unroll
    for (int s = 0; s < 2; s++) {
      int loff = s * 8192 + tid * 16;
      int row = loff >> 7;
      int sg = ((loff >> 4) & 7) ^ (row & 7);
      GL2LDS(Bhp + (long)row * DM + k0 + sg * 8, (char*)Bh + cur * 16384 + loff);
      GL2LDS(Bgp + (long)row * DM + k0 + sg * 8, (char*)Bg + cur * 16384 + loff);
    }
  };

  stage(0, 0);
  stage(1, 64);

  for (int t = 0; t < 16; t++) {
    const int cur = t & 1;
    if (t < 15) asm volatile("s_waitcnt vmcnt(8)" ::: "memory");
    else        asm volatile("s_waitcnt vmcnt(0)" ::: "memory");
    __builtin_amdgcn_s_barrier();
    asm volatile("" ::: "memory");

    const char* Ab  = (const char*)As + cur * 32768;
    const char* Bhb = (const char*)Bh + cur * 16384;
    const char* Bgb = (const char*)Bg + cur * 16384;

    bf16x8 af[4][2];
#pragma unroll
    for (int mi = 0; mi < 4; mi++)
#pragma unroll
      for (int ks = 0; ks < 2; ks++) {
        int row = wm * 64 + mi * 16 + (lane & 15);
        int seg = ks * 4 + (lane >> 4);
        af[mi][ks] = *(const bf16x8*)(Ab + row * 128 + ((seg ^ (row & 7)) << 4));
      }
#pragma unroll
    for (int j = 0; j < 4; j++) {
      bf16x8 bh[2], bg[2];
#pragma unroll
      for (int ks = 0; ks < 2; ks++) {
        int row = wn * 64 + j * 16 + (lane & 15);
        int seg = ks * 4 + (lane >> 4);
        int o = row * 128 + ((seg ^ (row & 7)) << 4);
        bh[ks] = *(const bf16x8*)(Bhb + o);
        bg[ks] = *(const bf16x8*)(Bgb + o);
      }
      __builtin_amdgcn_s_setprio(1);
#pragma unroll
      for (int mi = 0; mi < 4; mi++) {
        acc_h[mi][j] = __builtin_amdgcn_mfma_f32_16x16x32_bf16(af[mi][0], bh[0], acc_h[mi][j], 0, 0, 0);
        acc_h[mi][j] = __builtin_amdgcn_mfma_f32_16x16x32_bf16(af[mi][1], bh[1], acc_h[mi][j], 0, 0, 0);
        acc_g[mi][j] = __builtin_amdgcn_mfma_f32_16x16x32_bf16(af[mi][0], bg[0], acc_g[mi][j], 0, 0, 0);
        acc_g[mi][j] = __builtin_amdgcn_mfma_f32_16x16x32_bf16(af[mi][1], bg[1], acc_g[mi][j], 0, 0, 0);
      }
      __builtin_amdgcn_s_setprio(0);
      __builtin_amdgcn_s_barrier();
    }
    asm volatile("" ::: "memory");
    if (t + 2 < 16) stage(cur, (t + 2) * 64);
  }

#pragma unroll
  for (int j = 0; j < 4; j++) {
    const int col = nbase + wn * 64 + j * 16 + (lane & 15);
    const float bb0 = b0[e * DH + col];
    const float bb1 = b1[e * DH + col];
#pragma unroll
    for (int mi = 0; mi < 4; mi++) {
#pragma unroll
      for (int r = 0; r < 4; r++) {
        int mlocal = mt * 256 + wm * 64 + mi * 16 + (lane >> 4) * 4 + r;
        if (mlocal < cnt) {
          float h = acc_h[mi][j][r] + bb0;
          float g = acc_g[mi][j][r] + bb1;
          float a = h * (g / (1.f + __expf(-g)));
          aout[(long)(off_e + mlocal) * DH + col] = f2bf(a);
        }
      }
    }
  }
}

// ================= GEMM2: same schedule, BM=256 x BN=256, split-K=2 =====
__global__ __launch_bounds__(512, 2) void gemm2_kernel(
    const ushort* __restrict__ aout, const ushort* __restrict__ W2t,
    const int* __restrict__ offs, const int* __restrict__ rmeta,
    const float* __restrict__ rw, float* __restrict__ ybuf)
{
  const int flat = blockIdx.x;       // 0..511
  const int xcd = flat & 7;
  const int rest = flat >> 3;
  const int mt = rest & 7;
  const int g2 = rest >> 3;          // 0..7
  const int val = g2 * 8 + xcd;      // 0..63 ; mt-siblings share XCD
  const int e = val >> 3;
  const int r2 = val & 7;
  const int nt = r2 >> 1;            // 0..3
  const int kc = r2 & 1;

  const int off_e = offs[e];
  const int cnt = offs[e + 1] - off_e;
  if (mt * 256 >= cnt) return;
  const int nbase = nt * 256;
  const int kbase = kc * 2048;

  __shared__ ushort As[2 * 256 * 64];   // 64 KB (32 KB per buffer)
  __shared__ ushort Bs[2 * 256 * 64];   // 64 KB (32 KB per buffer)

  const int tid = threadIdx.x;
  const int lane = tid & 63;
  const int wave = tid >> 6;
  const int wm = wave & 1;           // 0..1 (128 rows each)
  const int wn = wave >> 1;          // 0..3 (64 cols each)

  const ushort* Ap = aout + (long)(off_e + mt * 256) * DH;
  const ushort* Bp = W2t + (long)e * DM * DH + (long)nbase * DH;

  f32x4 acc[8][4];
#pragma unroll
  for (int i = 0; i < 8; i++)
#pragma unroll
    for (int j = 0; j < 4; j++) acc[i][j] = (f32x4){0.f, 0.f, 0.f, 0.f};

  auto stage = [&](int cur, int k0) {
#pragma unroll
    for (int s = 0; s < 4; s++) {
      int loff = s * 8192 + tid * 16;
      int row = loff >> 7;
      int sg = ((loff >> 4) & 7) ^ (row & 7);
      long gelem = (long)row * DH + k0 + sg * 8;
      GL2LDS(Ap + gelem, (char*)As + cur * 32768 + loff);
      GL2LDS(Bp + gelem, (char*)Bs + cur * 32768 + loff);
    }
  };

  stage(0, kbase);
  stage(1, kbase + 64);

  for (int t = 0; t < 32; t++) {
    const int cur = t & 1;
    if (t < 31) asm volatile("s_waitcnt vmcnt(8)" ::: "memory");
    else        asm volatile("s_waitcnt vmcnt(0)" ::: "memory");
    __builtin_amdgcn_s_barrier();
    asm volatile("" ::: "memory");

    const char* Ab = (const char*)As + cur * 32768;
    const char* Bb = (const char*)Bs + cur * 32768;

    bf16x8 af[8][2];
#pragma unroll
    for (int mi = 0; mi < 8; mi++)
#pragma unroll
      for (int ks = 0; ks < 2; ks++) {
        int row = wm * 128 + mi * 16 + (lane & 15);
        int seg = ks * 4 + (lane >> 4);
        af[mi][ks] = *(const bf16x8*)(Ab + row * 128 + ((seg ^ (row & 7)) << 4));
      }
#pragma unroll
    for (int j = 0; j < 4; j++) {
      bf16x8 bf2[2];
#pragma unroll
      for (int ks = 0; ks < 2; ks++) {
        int row = wn * 64 + j * 16 + (lane & 15);
        int seg = ks * 4 + (lane >> 4);
        bf2[ks] = *(const bf16x8*)(Bb + row * 128 + ((seg ^ (row & 7)) << 4));
      }
      __builtin_amdgcn_s_setprio(1);
#pragma unroll
      for (int mi = 0; mi < 8; mi++) {
        acc[mi][j] = __builtin_amdgcn_mfma_f32_16x16x32_bf16(af[mi][0], bf2[0], acc[mi][j], 0, 0, 0);
        acc[mi][j] = __builtin_amdgcn_mfma_f32_16x16x32_bf16(af[mi][1], bf2[1], acc[mi][j], 0, 0, 0);
      }
      __builtin_amdgcn_s_setprio(0);
      __builtin_amdgcn_s_barrier();
    }
    asm volatile("" ::: "memory");
    if (t + 2 < 32) stage(cur, kbase + (t + 2) * 64);
  }

#pragma unroll
  for (int j = 0; j < 4; j++) {
    const int col = nbase + wn * 64 + j * 16 + (lane & 15);
#pragma unroll
    for (int mi = 0; mi < 8; mi++) {
#pragma unroll
      for (int r = 0; r < 4; r++) {
        int mlocal = mt * 256 + wm * 128 + mi * 16 + (lane >> 4) * 4 + r;
        if (mlocal < cnt) {
          int grow = off_e + mlocal;
          ybuf[((long)kc * 8192 + rmeta[grow]) * DM + col] = rw[grow] * acc[mi][j][r];
        }
      }
    }
  }
}

// ---------------- combine: split-K partials + both experts + bias ----------
__global__ __launch_bounds__(256) void combine_kernel(
    const float* __restrict__ ybuf, const int* __restrict__ tkE,
    const float* __restrict__ tkW, const float* __restrict__ b2,
    float* __restrict__ out)
{
  const int t = blockIdx.x;
  const int c = threadIdx.x * 4;
  const int ee = tkE[t];
  const int e0 = ee & 0xff, e1 = ee >> 8;
  const float w0 = tkW[2 * t], w1 = tkW[2 * t + 1];

  float4 acc = {0.f, 0.f, 0.f, 0.f};
#pragma unroll
  for (int kc = 0; kc < 2; kc++) {
#pragma unroll
    for (int k = 0; k < 2; k++) {
      const float4 v = *(const float4*)&ybuf[((long)kc * 8192 + 2 * t + k) * DM + c];
      acc.x += v.x; acc.y += v.y; acc.z += v.z; acc.w += v.w;
    }
  }
  const float4 p0 = *(const float4*)&b2[(long)e0 * DM + c];
  const float4 p1 = *(const float4*)&b2[(long)e1 * DM + c];
  acc.x += w0 * p0.x + w1 * p1.x;
  acc.y += w0 * p0.y + w1 * p1.y;
  acc.z += w0 * p0.z + w1 * p1.z;
  acc.w += w0 * p0.w + w1 * p1.w;
  *(float4*)&out[(long)t * DM + c] = acc;
}

extern "C" void kernel_launch(void* const* d_in, const int* in_sizes, int n_in,
                              void* d_out, int out_size, void* d_ws, size_t ws_size,
                              hipStream_t stream) {
  const float* x  = (const float*)d_in[0];
  const float* Wg = (const float*)d_in[1];
  const float* bg = (const float*)d_in[2];
  const float* W0 = (const float*)d_in[3];
  const float* b0 = (const float*)d_in[4];
  const float* W1 = (const float*)d_in[5];
  const float* b1 = (const float*)d_in[6];
  const float* W2 = (const float*)d_in[7];
  const float* b2 = (const float*)d_in[8];
  float* out = (float*)d_out;

  char* ws = (char*)d_ws;
  // ybuf ALIASES Wt01: Wt01 dead after gemm1; ybuf written by gemm2 after.
  ushort* Wt01 = (ushort*)(ws + 0);           // [8][8192][1024] bf16 = 134217728
  float*  ybuf = (float*)(ws + 0);            // [2][8192][1024] f32 =  67108864
  ushort* W2t  = (ushort*)(ws + 134217728);   // [8][1024][4096] bf16 = 67108864
  ushort* xg   = (ushort*)(ws + 201326592);   // [8448][1024] bf16 (pad for 256-tiles)
  ushort* aout = (ushort*)(ws + 218628096);   // [8448][4096] bf16
  int*    tkE  = (int*)(ws + 287834112);
  float*  tkW  = (float*)(ws + 287850496);
  int*    rmeta= (int*)(ws + 287883264);
  float*  rw   = (float*)(ws + 287916032);
  int*    gcnt = (int*)(ws + 287948800);
  int*    offs = gcnt + 8;
  int*    cursor = gcnt + 20;

  hipMemsetAsync(gcnt, 0, 32, stream);
  gate_kernel<<<NTOK / 4, 256, 0, stream>>>(x, Wg, bg, tkE, tkW, gcnt);
  scan_kernel<<<1, 64, 0, stream>>>(gcnt, offs, cursor);
  build_kernel<<<NTOK / 256, 256, 0, stream>>>(tkE, tkW, offs, cursor, rmeta, rw);
  gather_kernel<<<2 * NTOK, 256, 0, stream>>>(x, rmeta, xg);

  transpose_cvt<<<dim3(64, 16, 8), 256, 0, stream>>>(
      W0, Wt01, 1024, 4096, (long)1024 * 4096, (long)8192 * 1024);
  transpose_cvt<<<dim3(64, 16, 8), 256, 0, stream>>>(
      W1, Wt01 + (long)4096 * 1024, 1024, 4096, (long)1024 * 4096, (long)8192 * 1024);
  transpose_cvt<<<dim3(16, 64, 8), 256, 0, stream>>>(
      W2, W2t, 4096, 1024, (long)4096 * 1024, (long)1024 * 4096);

  gemm1_kernel<<<2048, 512, 0, stream>>>(xg, Wt01, b0, b1, offs, aout);
  gemm2_kernel<<<512, 512, 0, stream>>>(aout, W2t, offs, rmeta, rw, ybuf);
  combine_kernel<<<dim3(NTOK), 256, 0, stream>>>(ybuf, tkE, tkW, b2, out);
}

// Round 5
// 1059.506 us; speedup vs baseline: 1.0180x; 1.0180x over previous
//
#include <hip/hip_runtime.h>

#define NTOK 4096
#define DM 1024
#define DH 4096
#define NE 8

typedef __attribute__((ext_vector_type(8))) short bf16x8;
typedef __attribute__((ext_vector_type(4))) float f32x4;
typedef __attribute__((ext_vector_type(8))) unsigned short u16x8;

#define FENCE asm volatile("" ::: "memory")

__device__ __forceinline__ ushort f2bf(float f) {
  union { float f; unsigned u; } v; v.f = f;
  unsigned r = v.u + 0x7fffu + ((v.u >> 16) & 1u);
  return (ushort)(r >> 16);
}

#define GL2LDS(g, l) __builtin_amdgcn_global_load_lds( \
    (__attribute__((address_space(1))) const void*)(g), \
    (__attribute__((address_space(3))) void*)(l), 16, 0, 0)

// ---------------- gating: logits, top-2, softmax, counts ----------------
__global__ __launch_bounds__(256) void gate_kernel(
    const float* __restrict__ x, const float* __restrict__ Wg,
    const float* __restrict__ bg, int* __restrict__ tkE,
    float* __restrict__ tkW, int* __restrict__ gcnt)
{
  const int wave = threadIdx.x >> 6;
  const int lane = threadIdx.x & 63;
  const int t = blockIdx.x * 4 + wave;

  float acc[NE];
#pragma unroll
  for (int e = 0; e < NE; e++) acc[e] = 0.f;

  for (int i = 0; i < DM / 64; i++) {
    int d = i * 64 + lane;
    float xv = x[(long)t * DM + d];
#pragma unroll
    for (int e = 0; e < NE; e++) acc[e] += xv * Wg[d * NE + e];
  }
#pragma unroll
  for (int e = 0; e < NE; e++) {
#pragma unroll
    for (int off = 32; off; off >>= 1) acc[e] += __shfl_xor(acc[e], off, 64);
    acc[e] += bg[e];
  }
  int e0 = 0; float v0 = acc[0];
#pragma unroll
  for (int e = 1; e < NE; e++) if (acc[e] > v0) { v0 = acc[e]; e0 = e; }
  int e1 = -1; float v1 = -3.4e38f;
#pragma unroll
  for (int e = 0; e < NE; e++) if (e != e0 && acc[e] > v1) { v1 = acc[e]; e1 = e; }
  float w0 = 1.f / (1.f + __expf(v1 - v0));
  float w1 = 1.f - w0;
  if (lane == 0) {
    tkE[t] = e0 | (e1 << 8);
    tkW[2 * t] = w0;
    tkW[2 * t + 1] = w1;
    atomicAdd(&gcnt[e0], 1);
    atomicAdd(&gcnt[e1], 1);
  }
}

// ---------------- exclusive scan of counts ----------
__global__ void scan_kernel(const int* __restrict__ gcnt, int* __restrict__ offs,
                            int* __restrict__ cursor)
{
  if (threadIdx.x == 0) {
    int o = 0;
    for (int e = 0; e < NE; e++) { offs[e] = o; o += gcnt[e]; cursor[e] = 0; }
    offs[NE] = o;
  }
}

// ---------------- build packed row lists ----------------
__global__ __launch_bounds__(256) void build_kernel(
    const int* __restrict__ tkE, const float* __restrict__ tkW,
    const int* __restrict__ offs, int* __restrict__ cursor,
    int* __restrict__ rmeta, float* __restrict__ rw)
{
  int t = blockIdx.x * 256 + threadIdx.x;
  int ee = tkE[t];
#pragma unroll
  for (int k = 0; k < 2; k++) {
    int e = (k == 0) ? (ee & 0xff) : (ee >> 8);
    int pos = atomicAdd(&cursor[e], 1);
    int row = offs[e] + pos;
    rmeta[row] = t * 2 + k;
    rw[row] = tkW[t * 2 + k];
  }
}

// ---------------- gather x rows -> packed bf16 A matrix ----------------
__global__ __launch_bounds__(256) void gather_kernel(
    const float* __restrict__ x, const int* __restrict__ rmeta,
    ushort* __restrict__ xg)
{
  int row = blockIdx.x;
  int t = rmeta[row] >> 1;
  const float4* src = (const float4*)(x + (long)t * DM);
  float4 v = src[threadIdx.x];
  ushort4 o = { f2bf(v.x), f2bf(v.y), f2bf(v.z), f2bf(v.w) };
  *(ushort4*)(xg + (long)row * DM + threadIdx.x * 4) = o;
}

// ---------------- transpose + fp32->bf16 convert (64x64 tiles) ----------
__global__ __launch_bounds__(256) void transpose_cvt(
    const float* __restrict__ src, ushort* __restrict__ dst,
    int R, int C, long srcE, long dstE)
{
  __shared__ __align__(16) float tile[64][68];
  const int e = blockIdx.z;
  const int r0 = blockIdx.y * 64;
  const int c0 = blockIdx.x * 64;
  const float* s = src + (long)e * srcE;
  ushort* d = dst + (long)e * dstE;
  const int tid = threadIdx.x;
  const int lr = tid >> 4;      // 0..15
  const int lc4 = tid & 15;     // float4 col 0..15
#pragma unroll
  for (int p = 0; p < 4; p++) {
    int r = p * 16 + lr;
    float4 v = *(const float4*)&s[(long)(r0 + r) * C + c0 + lc4 * 4];
    *(float4*)&tile[r][lc4 * 4] = v;
  }
  __syncthreads();
  const int oc = tid >> 2;      // output row (= src col) 0..63
  const int seg = tid & 3;      // 16B segment
  u16x8 o0, o1;
#pragma unroll
  for (int j = 0; j < 8; j++) {
    o0[j] = f2bf(tile[seg * 8 + j][oc]);
    o1[j] = f2bf(tile[32 + seg * 8 + j][oc]);
  }
  ushort* dp = &d[(long)(c0 + oc) * R + r0];
  *(u16x8*)(dp + seg * 8) = o0;
  *(u16x8*)(dp + 32 + seg * 8) = o1;
}

// ================= GEMM1: faithful m201-style phase schedule ============
// BM=256 x BN=128(dual h,g), BK=64, 16 K-tiles. 8 waves (4M x 2N).
// Phase p: {ds_read issue, stage gl2lds issue} -> barrier -> lgkmcnt(0)
//          -> setprio(1) 16 MFMA setprio(0) [-> vmcnt @ phase3] -> barrier.
// Stage pipeline 2 tiles deep; steady-state vmcnt(4), never drained mid-loop.
__global__ __launch_bounds__(512, 2) void gemm1_kernel(
    const ushort* __restrict__ xg, const ushort* __restrict__ Wt01,
    const float* __restrict__ b0, const float* __restrict__ b1,
    const int* __restrict__ offs, ushort* __restrict__ aout)
{
  const int flat = blockIdx.x;       // 0..2047
  const int xcd = flat & 7;
  const int rest = flat >> 3;
  const int mt = rest & 7;           // 8 mt tiles of 256 rows
  const int g2 = rest >> 3;          // 0..31
  const int val = g2 * 8 + xcd;      // 0..255
  const int e = val >> 5;
  const int nt = val & 31;

  const int off_e = offs[e];
  const int cnt = offs[e + 1] - off_e;
  if (mt * 256 >= cnt) return;
  const int nbase = nt * 128;

  __shared__ ushort As[2 * 256 * 64];   // 64 KB (32 KB per buffer)
  __shared__ ushort Bh[2 * 128 * 64];   // 32 KB (16 KB per buffer)
  __shared__ ushort Bg[2 * 128 * 64];   // 32 KB (16 KB per buffer)

  const int tid = threadIdx.x;
  const int lane = tid & 63;
  const int wave = tid >> 6;
  const int wm = wave & 3;           // 0..3
  const int wn = wave >> 2;          // 0..1

  const ushort* Ap = xg + (long)(off_e + mt * 256) * DM;
  const ushort* Bhp = Wt01 + (long)e * (2 * DH) * DM + (long)nbase * DM;
  const ushort* Bgp = Bhp + (long)DH * DM;

  f32x4 acc_h[4][4], acc_g[4][4];
#pragma unroll
  for (int i = 0; i < 4; i++)
#pragma unroll
    for (int j = 0; j < 4; j++) {
      acc_h[i][j] = (f32x4){0.f, 0.f, 0.f, 0.f};
      acc_g[i][j] = (f32x4){0.f, 0.f, 0.f, 0.f};
    }

  // stage helpers: A in 2 halves (2 gl2lds each), B as one unit (4 gl2lds)
  auto stageA = [&](int cur, int k0, int half) {
#pragma unroll
    for (int s = 0; s < 2; s++) {
      int loff = (half * 2 + s) * 8192 + tid * 16;
      int row = loff >> 7;
      int sg = ((loff >> 4) & 7) ^ (row & 7);
      GL2LDS(Ap + (long)row * DM + k0 + sg * 8, (char*)As + cur * 32768 + loff);
    }
  };
  auto stageB = [&](int cur, int k0) {
#pragma unroll
    for (int s = 0; s < 2; s++) {
      int loff = s * 8192 + tid * 16;
      int row = loff >> 7;
      int sg = ((loff >> 4) & 7) ^ (row & 7);
      GL2LDS(Bhp + (long)row * DM + k0 + sg * 8, (char*)Bh + cur * 16384 + loff);
      GL2LDS(Bgp + (long)row * DM + k0 + sg * 8, (char*)Bg + cur * 16384 + loff);
    }
  };

  // prologue: S0 (A+B) and S1-A; vmcnt(4) waits S0, leaves S1-A in flight
  stageA(0, 0, 0); stageA(0, 0, 1); stageB(0, 0);
  stageA(1, 64, 0); stageA(1, 64, 1);
  asm volatile("s_waitcnt vmcnt(4)" ::: "memory");
  __builtin_amdgcn_s_barrier();

  bf16x8 af[4][2], bh[2], bg[2];

  for (int t = 0; t < 16; t++) {
    const int cur = t & 1;
    const char* Ab  = (const char*)As + cur * 32768;
    const char* Bhb = (const char*)Bh + cur * 16384;
    const char* Bgb = (const char*)Bg + cur * 16384;

#pragma unroll
    for (int j = 0; j < 4; j++) {
      // ---- issue this phase's ds_reads ----
      if (j == 0) {
#pragma unroll
        for (int mi = 0; mi < 4; mi++)
#pragma unroll
          for (int ks = 0; ks < 2; ks++) {
            int row = wm * 64 + mi * 16 + (lane & 15);
            int seg = ks * 4 + (lane >> 4);
            af[mi][ks] = *(const bf16x8*)(Ab + row * 128 + ((seg ^ (row & 7)) << 4));
          }
      }
      {
        int row = wn * 64 + j * 16 + (lane & 15);
#pragma unroll
        for (int ks = 0; ks < 2; ks++) {
          int seg = ks * 4 + (lane >> 4);
          int o = row * 128 + ((seg ^ (row & 7)) << 4);
          bh[ks] = *(const bf16x8*)(Bhb + o);
          bg[ks] = *(const bf16x8*)(Bgb + o);
        }
      }
      if (j == 0) asm volatile("s_waitcnt lgkmcnt(8)" ::: "memory");
      // ---- issue this phase's stage portion ----
      if (j == 1 && t + 1 < 16) stageB(cur ^ 1, (t + 1) * 64);
      if (j == 2 && t + 2 < 16) stageA(cur, (t + 2) * 64, 0);
      if (j == 3 && t + 2 < 16) stageA(cur, (t + 2) * 64, 1);
      FENCE;
      __builtin_amdgcn_s_barrier();
      asm volatile("s_waitcnt lgkmcnt(0)" ::: "memory");
      __builtin_amdgcn_sched_barrier(0);
      __builtin_amdgcn_s_setprio(1);
#pragma unroll
      for (int mi = 0; mi < 4; mi++) {
        acc_h[mi][j] = __builtin_amdgcn_mfma_f32_16x16x32_bf16(af[mi][0], bh[0], acc_h[mi][j], 0, 0, 0);
        acc_h[mi][j] = __builtin_amdgcn_mfma_f32_16x16x32_bf16(af[mi][1], bh[1], acc_h[mi][j], 0, 0, 0);
        acc_g[mi][j] = __builtin_amdgcn_mfma_f32_16x16x32_bf16(af[mi][0], bg[0], acc_g[mi][j], 0, 0, 0);
        acc_g[mi][j] = __builtin_amdgcn_mfma_f32_16x16x32_bf16(af[mi][1], bg[1], acc_g[mi][j], 0, 0, 0);
      }
      __builtin_amdgcn_s_setprio(0);
      if (j == 3) {
        if (t < 14)       asm volatile("s_waitcnt vmcnt(4)" ::: "memory");
        else if (t == 14) asm volatile("s_waitcnt vmcnt(0)" ::: "memory");
      }
      FENCE;
      __builtin_amdgcn_s_barrier();
    }
  }

#pragma unroll
  for (int j = 0; j < 4; j++) {
    const int col = nbase + wn * 64 + j * 16 + (lane & 15);
    const float bb0 = b0[e * DH + col];
    const float bb1 = b1[e * DH + col];
#pragma unroll
    for (int mi = 0; mi < 4; mi++) {
#pragma unroll
      for (int r = 0; r < 4; r++) {
        int mlocal = mt * 256 + wm * 64 + mi * 16 + (lane >> 4) * 4 + r;
        if (mlocal < cnt) {
          float h = acc_h[mi][j][r] + bb0;
          float g = acc_g[mi][j][r] + bb1;
          float a = h * (g / (1.f + __expf(-g)));
          aout[(long)(off_e + mlocal) * DH + col] = f2bf(a);
        }
      }
    }
  }
}

// ================= GEMM2: same schedule, BM=256 x BN=256, split-K=2 =====
__global__ __launch_bounds__(512, 2) void gemm2_kernel(
    const ushort* __restrict__ aout, const ushort* __restrict__ W2t,
    const int* __restrict__ offs, const int* __restrict__ rmeta,
    const float* __restrict__ rw, float* __restrict__ ybuf)
{
  const int flat = blockIdx.x;       // 0..511
  const int xcd = flat & 7;
  const int rest = flat >> 3;
  const int mt = rest & 7;
  const int g2 = rest >> 3;          // 0..7
  const int val = g2 * 8 + xcd;      // 0..63
  const int e = val >> 3;
  const int r2 = val & 7;
  const int nt = r2 >> 1;            // 0..3
  const int kc = r2 & 1;

  const int off_e = offs[e];
  const int cnt = offs[e + 1] - off_e;
  if (mt * 256 >= cnt) return;
  const int nbase = nt * 256;
  const int kbase = kc * 2048;

  __shared__ ushort As[2 * 256 * 64];   // 64 KB (32 KB per buffer)
  __shared__ ushort Bs[2 * 256 * 64];   // 64 KB (32 KB per buffer)

  const int tid = threadIdx.x;
  const int lane = tid & 63;
  const int wave = tid >> 6;
  const int wm = wave & 1;           // 0..1 (128 rows each)
  const int wn = wave >> 1;          // 0..3 (64 cols each)

  const ushort* Ap = aout + (long)(off_e + mt * 256) * DH;
  const ushort* Bp = W2t + (long)e * DM * DH + (long)nbase * DH;

  f32x4 acc[8][4];
#pragma unroll
  for (int i = 0; i < 8; i++)
#pragma unroll
    for (int j = 0; j < 4; j++) acc[i][j] = (f32x4){0.f, 0.f, 0.f, 0.f};

  auto stageA = [&](int cur, int k0, int half) {
#pragma unroll
    for (int s = 0; s < 2; s++) {
      int loff = (half * 2 + s) * 8192 + tid * 16;
      int row = loff >> 7;
      int sg = ((loff >> 4) & 7) ^ (row & 7);
      GL2LDS(Ap + (long)row * DH + k0 + sg * 8, (char*)As + cur * 32768 + loff);
    }
  };
  auto stageB = [&](int cur, int k0) {
#pragma unroll
    for (int s = 0; s < 4; s++) {
      int loff = s * 8192 + tid * 16;
      int row = loff >> 7;
      int sg = ((loff >> 4) & 7) ^ (row & 7);
      GL2LDS(Bp + (long)row * DH + k0 + sg * 8, (char*)Bs + cur * 32768 + loff);
    }
  };

  stageA(0, kbase, 0); stageA(0, kbase, 1); stageB(0, kbase);
  stageA(1, kbase + 64, 0); stageA(1, kbase + 64, 1);
  asm volatile("s_waitcnt vmcnt(4)" ::: "memory");
  __builtin_amdgcn_s_barrier();

  bf16x8 af[8][2], bf2[2];

  for (int t = 0; t < 32; t++) {
    const int cur = t & 1;
    const char* Ab = (const char*)As + cur * 32768;
    const char* Bb = (const char*)Bs + cur * 32768;

#pragma unroll
    for (int j = 0; j < 4; j++) {
      if (j == 0) {
#pragma unroll
        for (int mi = 0; mi < 8; mi++)
#pragma unroll
          for (int ks = 0; ks < 2; ks++) {
            int row = wm * 128 + mi * 16 + (lane & 15);
            int seg = ks * 4 + (lane >> 4);
            af[mi][ks] = *(const bf16x8*)(Ab + row * 128 + ((seg ^ (row & 7)) << 4));
          }
      }
      {
        int row = wn * 64 + j * 16 + (lane & 15);
#pragma unroll
        for (int ks = 0; ks < 2; ks++) {
          int seg = ks * 4 + (lane >> 4);
          bf2[ks] = *(const bf16x8*)(Bb + row * 128 + ((seg ^ (row & 7)) << 4));
        }
      }
      if (j == 0) asm volatile("s_waitcnt lgkmcnt(8)" ::: "memory");
      if (j == 1 && t + 1 < 32) stageB(cur ^ 1, kbase + (t + 1) * 64);
      if (j == 2 && t + 2 < 32) stageA(cur, kbase + (t + 2) * 64, 0);
      if (j == 3 && t + 2 < 32) stageA(cur, kbase + (t + 2) * 64, 1);
      FENCE;
      __builtin_amdgcn_s_barrier();
      asm volatile("s_waitcnt lgkmcnt(0)" ::: "memory");
      __builtin_amdgcn_sched_barrier(0);
      __builtin_amdgcn_s_setprio(1);
#pragma unroll
      for (int mi = 0; mi < 8; mi++) {
        acc[mi][j] = __builtin_amdgcn_mfma_f32_16x16x32_bf16(af[mi][0], bf2[0], acc[mi][j], 0, 0, 0);
        acc[mi][j] = __builtin_amdgcn_mfma_f32_16x16x32_bf16(af[mi][1], bf2[1], acc[mi][j], 0, 0, 0);
      }
      __builtin_amdgcn_s_setprio(0);
      if (j == 3) {
        if (t < 30)       asm volatile("s_waitcnt vmcnt(4)" ::: "memory");
        else if (t == 30) asm volatile("s_waitcnt vmcnt(0)" ::: "memory");
      }
      FENCE;
      __builtin_amdgcn_s_barrier();
    }
  }

#pragma unroll
  for (int j = 0; j < 4; j++) {
    const int col = nbase + wn * 64 + j * 16 + (lane & 15);
#pragma unroll
    for (int mi = 0; mi < 8; mi++) {
#pragma unroll
      for (int r = 0; r < 4; r++) {
        int mlocal = mt * 256 + wm * 128 + mi * 16 + (lane >> 4) * 4 + r;
        if (mlocal < cnt) {
          int grow = off_e + mlocal;
          ybuf[((long)kc * 8192 + rmeta[grow]) * DM + col] = rw[grow] * acc[mi][j][r];
        }
      }
    }
  }
}

// ---------------- combine: split-K partials + both experts + bias ----------
__global__ __launch_bounds__(256) void combine_kernel(
    const float* __restrict__ ybuf, const int* __restrict__ tkE,
    const float* __restrict__ tkW, const float* __restrict__ b2,
    float* __restrict__ out)
{
  const int t = blockIdx.x;
  const int c = threadIdx.x * 4;
  const int ee = tkE[t];
  const int e0 = ee & 0xff, e1 = ee >> 8;
  const float w0 = tkW[2 * t], w1 = tkW[2 * t + 1];

  float4 acc = {0.f, 0.f, 0.f, 0.f};
#pragma unroll
  for (int kc = 0; kc < 2; kc++) {
#pragma unroll
    for (int k = 0; k < 2; k++) {
      const float4 v = *(const float4*)&ybuf[((long)kc * 8192 + 2 * t + k) * DM + c];
      acc.x += v.x; acc.y += v.y; acc.z += v.z; acc.w += v.w;
    }
  }
  const float4 p0 = *(const float4*)&b2[(long)e0 * DM + c];
  const float4 p1 = *(const float4*)&b2[(long)e1 * DM + c];
  acc.x += w0 * p0.x + w1 * p1.x;
  acc.y += w0 * p0.y + w1 * p1.y;
  acc.z += w0 * p0.z + w1 * p1.z;
  acc.w += w0 * p0.w + w1 * p1.w;
  *(float4*)&out[(long)t * DM + c] = acc;
}

extern "C" void kernel_launch(void* const* d_in, const int* in_sizes, int n_in,
                              void* d_out, int out_size, void* d_ws, size_t ws_size,
                              hipStream_t stream) {
  const float* x  = (const float*)d_in[0];
  const float* Wg = (const float*)d_in[1];
  const float* bg = (const float*)d_in[2];
  const float* W0 = (const float*)d_in[3];
  const float* b0 = (const float*)d_in[4];
  const float* W1 = (const float*)d_in[5];
  const float* b1 = (const float*)d_in[6];
  const float* W2 = (const float*)d_in[7];
  const float* b2 = (const float*)d_in[8];
  float* out = (float*)d_out;

  char* ws = (char*)d_ws;
  // ybuf ALIASES Wt01: Wt01 dead after gemm1; ybuf written by gemm2 after.
  ushort* Wt01 = (ushort*)(ws + 0);           // [8][8192][1024] bf16 = 134217728
  float*  ybuf = (float*)(ws + 0);            // [2][8192][1024] f32 =  67108864
  ushort* W2t  = (ushort*)(ws + 134217728);   // [8][1024][4096] bf16 = 67108864
  ushort* xg   = (ushort*)(ws + 201326592);   // [8448][1024] bf16 (pad for 256-tiles)
  ushort* aout = (ushort*)(ws + 218628096);   // [8448][4096] bf16
  int*    tkE  = (int*)(ws + 287834112);
  float*  tkW  = (float*)(ws + 287850496);
  int*    rmeta= (int*)(ws + 287883264);
  float*  rw   = (float*)(ws + 287916032);
  int*    gcnt = (int*)(ws + 287948800);
  int*    offs = gcnt + 8;
  int*    cursor = gcnt + 20;

  hipMemsetAsync(gcnt, 0, 32, stream);
  gate_kernel<<<NTOK / 4, 256, 0, stream>>>(x, Wg, bg, tkE, tkW, gcnt);
  scan_kernel<<<1, 64, 0, stream>>>(gcnt, offs, cursor);
  build_kernel<<<NTOK / 256, 256, 0, stream>>>(tkE, tkW, offs, cursor, rmeta, rw);
  gather_kernel<<<2 * NTOK, 256, 0, stream>>>(x, rmeta, xg);

  transpose_cvt<<<dim3(64, 16, 8), 256, 0, stream>>>(
      W0, Wt01, 1024, 4096, (long)1024 * 4096, (long)8192 * 1024);
  transpose_cvt<<<dim3(64, 16, 8), 256, 0, stream>>>(
      W1, Wt01 + (long)4096 * 1024, 1024, 4096, (long)1024 * 4096, (long)8192 * 1024);
  transpose_cvt<<<dim3(16, 64, 8), 256, 0, stream>>>(
      W2, W2t, 4096, 1024, (long)4096 * 1024, (long)1024 * 4096);

  gemm1_kernel<<<2048, 512, 0, stream>>>(xg, Wt01, b0, b1, offs, aout);
  gemm2_kernel<<<512, 512, 0, stream>>>(aout, W2t, offs, rmeta, rw, ybuf);
  combine_kernel<<<dim3(NTOK), 256, 0, stream>>>(ybuf, tkE, tkW, b2, out);
}